// Round 9
// baseline (1748.860 us; speedup 1.0000x reference)
//
#include <hip/hip_runtime.h>
#include <math.h>

#define N_B 16
#define T_LEN 4096

typedef short bf16x8 __attribute__((ext_vector_type(8)));
typedef float f32x4  __attribute__((ext_vector_type(4)));

// ---- workspace layout (float offsets) — r4-proven fit ----
static const size_t OFF_A    = 0;            // 16*128*4096
static const size_t OFF_B    = 8388608;      // 16*256*4096
static const size_t OFF_Z    = 25165824;     // 16*64*4096
static const size_t OFF_WT1  = 29360128;
static const size_t OFF_WT2  = 29390848;
static const size_t OFF_WT3  = 29489152;
static const size_t OFF_WD1  = 29505536;
static const size_t OFF_WD2  = 29554688;
static const size_t OFF_WD3  = 29652992;
static const size_t OFF_C2   = 29683712;
static const size_t OFF_ST   = 29684736;
static const size_t OFF_LOSS = 29685760;

__device__ inline unsigned short f2bf(float f) {
    unsigned u = __float_as_uint(f);
    unsigned r = (u + 0x7FFFu + ((u >> 16) & 1u)) >> 16;
    return (unsigned short)r;
}
__device__ inline float bf2f(unsigned short h) {
    return __uint_as_float(((unsigned)h) << 16);
}

// ---- weight transpose helper: w[CO][CI][KS] -> wT[KS][CI][CO] (f32) ----
template<int C_OUT, int C_IN, int KS>
__device__ inline void tw(const float* __restrict__ w, float* __restrict__ wT, int e) {
    int co  = e / (C_IN * KS);
    int rem = e - co * (C_IN * KS);
    int ci  = rem / KS;
    int k   = rem - ci * KS;
    wT[(k * C_IN + ci) * C_OUT + co] = w[e];
}

__global__ __launch_bounds__(256) void prep_k(
        const float* __restrict__ w1, const float* __restrict__ w2,
        const float* __restrict__ w3, const float* __restrict__ wd1,
        const float* __restrict__ wd2, const float* __restrict__ wd3,
        const float* __restrict__ cb, float* wsf) {
    int e = blockIdx.x * 256 + threadIdx.x;
    if (e < 30720)        tw<128,  80, 3>(w1,  wsf + OFF_WT1, e);
    else if (e < 129024)  tw<256, 128, 3>(w2,  wsf + OFF_WT2, e - 30720);
    else if (e < 145408)  tw< 64, 256, 1>(w3,  wsf + OFF_WT3, e - 129024);
    else if (e < 194560)  tw<256,  64, 3>(wd1, wsf + OFF_WD1, e - 145408);
    else if (e < 292864)  tw<128, 256, 3>(wd2, wsf + OFF_WD2, e - 194560);
    else if (e < 323584)  tw< 80, 128, 3>(wd3, wsf + OFF_WD3, e - 292864);
    else if (e < 324096) {
        int c = e - 323584;
        const float* p = cb + (size_t)c * 64;
        double s = 0.0;
        for (int d = 0; d < 64; ++d) { double v = p[d]; s += v * v; }
        wsf[OFF_C2 + c] = (float)s;
    } else if (e == 324096) {
        *(double*)(wsf + OFF_LOSS) = 0.0;
    }
}

// ---- encoder conv1d: f64-vector accumulation, f64 LDS staging (bit-exact) ----
// Optional fused BN-stats partial sums of the f32 output into `partial`
// (per-(channel, block) sums; deterministic shfl tree).
template<int C_IN, int C_OUT, int KS, bool BN_IN, bool HAS_STATS>
__global__ __launch_bounds__(256) void conv_k(
        const float* __restrict__ x, const float* __restrict__ wT,
        const float* __restrict__ bias, const double2* __restrict__ stats,
        float* __restrict__ out, double2* __restrict__ partial, int NP) {
    constexpr int T_TILE = 128;
    constexpr int CI_CH  = (KS == 3) ? 16 : 32;
    constexpr int XCOLS  = T_TILE + KS - 1;
    constexpr int XROW   = (KS == 3) ? 132 : 130;
    constexpr int WROWS  = 66;

    __shared__ __align__(16) double xs[CI_CH * XROW];
    __shared__ __align__(16) double ws[KS * CI_CH * WROWS];

    const int tid = threadIdx.x;
    const int tx  = tid & 15;
    const int ty  = tid >> 4;
    const int n    = blockIdx.x >> 5;
    const int t0   = (blockIdx.x & 31) * T_TILE;
    const int co0  = blockIdx.y * 64;

    double acc[4][8];
#pragma unroll
    for (int i = 0; i < 4; ++i)
#pragma unroll
        for (int j = 0; j < 8; ++j) acc[i][j] = 0.0;

    for (int ci0 = 0; ci0 < C_IN; ci0 += CI_CH) {
        __syncthreads();
        for (int e = tid; e < CI_CH * XCOLS; e += 256) {
            int ci = e / XCOLS;
            int tt = e - ci * XCOLS;
            int cig = ci0 + ci;
            int gt  = t0 + tt - (KS / 2);
            float v = 0.f;
            if (gt >= 0 && gt < T_LEN) {
                v = x[((size_t)(n * C_IN + cig)) * T_LEN + gt];
                if (BN_IN) {
                    double2 s = stats[cig];
                    double vv = fma((double)v, s.x, s.y);
                    v = (float)fmax(vv, 0.0);   // f32 storage contract
                }
            }
            xs[ci * XROW + tt] = (double)v;
        }
        for (int e = tid; e < KS * CI_CH * 64; e += 256) {
            int co = e & 63;
            int r  = e >> 6;
            int ci = r & (CI_CH - 1);
            int k  = (KS == 3) ? (r >> ((CI_CH == 16) ? 4 : 5)) : 0;
            float v = 0.f;
            if (co0 + co < C_OUT)
                v = wT[((size_t)(k * C_IN + ci0 + ci)) * C_OUT + co0 + co];
            ws[(k * CI_CH + ci) * WROWS + co] = (double)v;
        }
        __syncthreads();

        for (int ci = 0; ci < CI_CH; ++ci) {
            double xv[10];
            {
                const double* xr = &xs[ci * XROW + tx * 8];
#pragma unroll
                for (int j = 0; j < 8; ++j) xv[j] = xr[j];
                if (KS == 3) { xv[8] = xr[8]; xv[9] = xr[9]; }
                else { xv[8] = 0.0; xv[9] = 0.0; }
            }
            double wa[KS][4];
#pragma unroll
            for (int k = 0; k < KS; ++k) {
                const double* wr = &ws[(k * CI_CH + ci) * WROWS + ty * 4];
#pragma unroll
                for (int i = 0; i < 4; ++i) wa[k][i] = wr[i];
            }
#pragma unroll
            for (int k = 0; k < KS; ++k)
#pragma unroll
                for (int i = 0; i < 4; ++i)
#pragma unroll
                    for (int j = 0; j < 8; ++j)
                        acc[i][j] = fma(wa[k][i], xv[j + k], acc[i][j]);
        }
    }

    const size_t tb = (size_t)t0 + (size_t)tx * 8;
#pragma unroll
    for (int i = 0; i < 4; ++i) {
        int co = co0 + ty * 4 + i;
        if (co < C_OUT) {
            double bv = (double)bias[co];
            float* o = out + ((size_t)(n * C_OUT + co)) * T_LEN + tb;
            float r[8];
#pragma unroll
            for (int j = 0; j < 8; ++j) r[j] = (float)(acc[i][j] + bv);
            *(float4*)&o[0] = make_float4(r[0], r[1], r[2], r[3]);
            *(float4*)&o[4] = make_float4(r[4], r[5], r[6], r[7]);
            if (HAS_STATS) {
                double s1 = 0.0, s2 = 0.0;
#pragma unroll
                for (int j = 0; j < 8; ++j) {
                    double v = (double)r[j];
                    s1 += v; s2 += v * v;
                }
#pragma unroll
                for (int s = 8; s > 0; s >>= 1) {
                    s1 += __shfl_down(s1, s, 16);
                    s2 += __shfl_down(s2, s, 16);
                }
                if (tx == 0)
                    partial[(size_t)co * NP + blockIdx.x] = make_double2(s1, s2);
            }
        }
    }
}

// ---- decoder conv1d via split-bf16 MFMA (probe-verified, f32 fallback) ----
template<int C_IN, int C_OUT, bool BN_IN, bool HAS_STATS>
__global__ __launch_bounds__(256) void mbconv_k(
        const float* __restrict__ x, const float* __restrict__ wT,
        const float* __restrict__ bias, const double2* __restrict__ stats,
        float* __restrict__ out, double2* __restrict__ partial, int NP) {
    constexpr int CI_CH = 32;
    constexpr int RS    = 72;
    constexpr int LO    = 40;

    __shared__ __align__(16) short xs[66 * RS];
    __shared__ __align__(16) short ws[192 * RS];
    __shared__ int okf;

    const int tid  = threadIdx.x;
    const int lane = tid & 63;
    const int wv   = tid >> 6;
    const int ln   = lane & 15;
    const int q    = lane >> 4;

    const int n   = blockIdx.x >> 6;
    const int t0  = (blockIdx.x & 63) * 64;
    const int co0 = blockIdx.y * 64;

    bool ok = true;
    {
        bf16x8 pa, pb;
#pragma unroll
        for (int j = 0; j < 8; ++j) {
            int kk = q * 8 + j;
            pa[j] = (short)f2bf((float)(ln + 2 * kk));
            pb[j] = (short)f2bf((float)(ln + 3 * kk));
        }
        f32x4 pd = {0.f, 0.f, 0.f, 0.f};
        pd = __builtin_amdgcn_mfma_f32_16x16x32_bf16(pa, pb, pd, 0, 0, 0);
#pragma unroll
        for (int r = 0; r < 4; ++r) {
            int m = q * 4 + r;
            float e = (float)(32 * m * ln + 1488 * m + 992 * ln + 62496);
            if (pd[r] != e) ok = false;
        }
    }
    if (tid == 0) okf = 1;
    __syncthreads();
    if (!ok) okf = 0;
    __syncthreads();
    const bool okp = (okf != 0);

    f32x4 acc[4];
#pragma unroll
    for (int tt = 0; tt < 4; ++tt)
#pragma unroll
        for (int i = 0; i < 4; ++i) acc[tt][i] = 0.f;

    for (int ci0 = 0; ci0 < C_IN; ci0 += CI_CH) {
        __syncthreads();
        for (int e = tid; e < CI_CH * 66; e += 256) {
            int ci   = e / 66;
            int trow = e - ci * 66;
            int gt   = t0 - 1 + trow;
            float v  = 0.f;
            if (gt >= 0 && gt < T_LEN) {
                v = x[((size_t)(n * C_IN + ci0 + ci)) * T_LEN + gt];
                if (BN_IN) {
                    double2 s = stats[ci0 + ci];
                    v = (float)fmax(fma((double)v, s.x, s.y), 0.0);
                }
            }
            unsigned short h = f2bf(v);
            unsigned short l = f2bf(v - bf2f(h));
            xs[trow * RS + ci]      = (short)h;
            xs[trow * RS + LO + ci] = (short)l;
        }
        for (int e = tid; e < 3 * CI_CH * 64; e += 256) {
            int co = e & 63;
            int rr = e >> 6;
            int k  = rr >> 5;
            int ci = rr & 31;
            float v = 0.f;
            if (co0 + co < C_OUT)
                v = wT[((size_t)(k * C_IN + ci0 + ci)) * C_OUT + co0 + co];
            unsigned short h = f2bf(v);
            unsigned short l = f2bf(v - bf2f(h));
            ws[(k * 64 + co) * RS + ci]      = (short)h;
            ws[(k * 64 + co) * RS + LO + ci] = (short)l;
        }
        __syncthreads();

        if (okp) {
#pragma unroll
            for (int k = 0; k < 3; ++k) {
                const short* wr = &ws[(k * 64 + wv * 16 + ln) * RS + q * 8];
                bf16x8 ah = *(const bf16x8*)&wr[0];
                bf16x8 al = *(const bf16x8*)&wr[LO];
#pragma unroll
                for (int tt = 0; tt < 4; ++tt) {
                    const short* xr = &xs[(tt * 16 + ln + k) * RS + q * 8];
                    bf16x8 bh = *(const bf16x8*)&xr[0];
                    bf16x8 bl = *(const bf16x8*)&xr[LO];
                    acc[tt] = __builtin_amdgcn_mfma_f32_16x16x32_bf16(ah, bh, acc[tt], 0, 0, 0);
                    acc[tt] = __builtin_amdgcn_mfma_f32_16x16x32_bf16(ah, bl, acc[tt], 0, 0, 0);
                    acc[tt] = __builtin_amdgcn_mfma_f32_16x16x32_bf16(al, bh, acc[tt], 0, 0, 0);
                }
            }
        } else {
            for (int k = 0; k < 3; ++k)
                for (int ci = 0; ci < CI_CH; ++ci) {
                    float wr[4], xv[4];
#pragma unroll
                    for (int r = 0; r < 4; ++r) {
                        const short* p = &ws[(k * 64 + wv * 16 + q * 4 + r) * RS];
                        wr[r] = bf2f((unsigned short)p[ci]) + bf2f((unsigned short)p[LO + ci]);
                    }
#pragma unroll
                    for (int tt = 0; tt < 4; ++tt) {
                        const short* p = &xs[(tt * 16 + ln + k) * RS];
                        xv[tt] = bf2f((unsigned short)p[ci]) + bf2f((unsigned short)p[LO + ci]);
                    }
#pragma unroll
                    for (int tt = 0; tt < 4; ++tt)
#pragma unroll
                        for (int r = 0; r < 4; ++r)
                            acc[tt][r] = fmaf(wr[r], xv[tt], acc[tt][r]);
                }
        }
    }

#pragma unroll
    for (int r = 0; r < 4; ++r) {
        int co = co0 + wv * 16 + q * 4 + r;
        double s1 = 0.0, s2 = 0.0;
#pragma unroll
        for (int tt = 0; tt < 4; ++tt) {
            if (co < C_OUT) {
                float v = acc[tt][r] + bias[co];
                out[((size_t)(n * C_OUT + co)) * T_LEN + t0 + tt * 16 + ln] = v;
                if (HAS_STATS) { double dv = (double)v; s1 += dv; s2 += dv * dv; }
            }
        }
        if (HAS_STATS) {
#pragma unroll
            for (int s = 8; s > 0; s >>= 1) {
                s1 += __shfl_down(s1, s, 16);
                s2 += __shfl_down(s2, s, 16);
            }
            if (ln == 0 && co < C_OUT)
                partial[(size_t)co * NP + blockIdx.x] = make_double2(s1, s2);
        }
    }
}

// ---- BN stats combine: sum P partials per channel (fixed order) -> scale/shift.
// Optional fin: extra last block writes the vq loss output.
__global__ __launch_bounds__(256) void stats2_k(
        const double2* __restrict__ part, int C, int P,
        const float* __restrict__ g, const float* __restrict__ b,
        double2* __restrict__ stats, const double* __restrict__ loss,
        float* __restrict__ out0) {
    if (out0 && blockIdx.x == gridDim.x - 1) {
        if (threadIdx.x == 0)
            *out0 = (float)(1.25 * (*loss) / 4194304.0);
        return;
    }
    int c = blockIdx.x * 256 + threadIdx.x;
    if (c >= C) return;
    double s1 = 0.0, s2 = 0.0;
    const double2* p = part + (size_t)c * P;
    for (int i = 0; i < P; ++i) { s1 += p[i].x; s2 += p[i].y; }
    double m   = s1 / 65536.0;
    double var = s2 / 65536.0 - m * m;
    double sc  = (double)g[c] / sqrt(var + 1e-5);
    stats[c] = make_double2(sc, (double)b[c] - m * sc);
}

// ---- VQ: replicate the reference's f32 d2 formula exactly ----
__global__ __launch_bounds__(256) void vq_k(
        const float* z, const float* __restrict__ cb,
        const float* __restrict__ c2, float* q,
        float* __restrict__ idx_out, double* __restrict__ loss) {
    __shared__ __align__(16) float zs[64 * 68];
    __shared__ __align__(16) float cs[64 * 68];
    __shared__ float  szf[64];
    __shared__ float  redS[64 * 16];
    __shared__ int    redI[64 * 16];
    __shared__ int    idxs[64];
    __shared__ double dred[256];

    const int tid = threadIdx.x;
    const int tx  = tid & 15, ty = tid >> 4;
    const int n   = blockIdx.x >> 6;
    const int t0  = (blockIdx.x & 63) * 64;

    for (int e = tid; e < 4096; e += 256) {
        int t = e & 63, d = e >> 6;
        zs[t * 68 + d] = z[((size_t)(n * 64 + d)) * T_LEN + t0 + t];
    }
    __syncthreads();
    if (tid < 64) {
        double s = 0.0;
        const float* zr = &zs[tid * 68];
        for (int d = 0; d < 64; ++d) { double v = zr[d]; s += v * v; }
        szf[tid] = (float)s;
    }

    float best[4];
    int bidx[4];
#pragma unroll
    for (int i = 0; i < 4; ++i) { best[i] = 3.0e38f; bidx[i] = 1 << 30; }

    for (int ch = 0; ch < 8; ++ch) {
        __syncthreads();
        for (int e = tid; e < 4096; e += 256) {
            int d = e & 63, c = e >> 6;
            cs[c * 68 + d] = cb[((size_t)(ch * 64 + c)) * 64 + d];
        }
        __syncthreads();

        double acc[4][4];
#pragma unroll
        for (int i = 0; i < 4; ++i)
#pragma unroll
            for (int j = 0; j < 4; ++j) acc[i][j] = 0.0;

        for (int d = 0; d < 64; d += 4) {
            float4 zv[4], cv[4];
#pragma unroll
            for (int i = 0; i < 4; ++i)
                zv[i] = *(const float4*)&zs[(tx + 16 * i) * 68 + d];
#pragma unroll
            for (int j = 0; j < 4; ++j)
                cv[j] = *(const float4*)&cs[(ty + 16 * j) * 68 + d];
#pragma unroll
            for (int i = 0; i < 4; ++i)
#pragma unroll
                for (int j = 0; j < 4; ++j) {
                    acc[i][j] = fma((double)zv[i].x, (double)cv[j].x, acc[i][j]);
                    acc[i][j] = fma((double)zv[i].y, (double)cv[j].y, acc[i][j]);
                    acc[i][j] = fma((double)zv[i].z, (double)cv[j].z, acc[i][j]);
                    acc[i][j] = fma((double)zv[i].w, (double)cv[j].w, acc[i][j]);
                }
        }
#pragma unroll
        for (int j = 0; j < 4; ++j) {
            int cg = ch * 64 + ty + 16 * j;
            float cc = c2[cg];
#pragma unroll
            for (int i = 0; i < 4; ++i) {
                float m32 = (float)acc[i][j];
                float A   = szf[tx + 16 * i] + cc;
                float s   = A - 2.0f * m32;
                if (s < best[i] || (s == best[i] && cg < bidx[i])) {
                    best[i] = s; bidx[i] = cg;
                }
            }
        }
    }
#pragma unroll
    for (int i = 0; i < 4; ++i) {
        redS[(tx + 16 * i) * 16 + ty] = best[i];
        redI[(tx + 16 * i) * 16 + ty] = bidx[i];
    }
    __syncthreads();

    if (tid < 64) {
        int t = tid;
        float bs = 3.0e38f; int bi = 1 << 30;
        for (int y2 = 0; y2 < 16; ++y2) {
            float v = redS[t * 16 + y2];
            int vi  = redI[t * 16 + y2];
            if (v < bs || (v == bs && vi < bi)) { bs = v; bi = vi; }
        }
        idxs[t] = bi;
        idx_out[(size_t)n * T_LEN + t0 + t] = (float)bi;
    }
    __syncthreads();

    {
        int g = tid >> 6, t = tid & 63;
        int bi = idxs[t];
        double ls = 0.0;
        for (int dd = 0; dd < 16; ++dd) {
            int d = g * 16 + dd;
            float qv = cb[(size_t)bi * 64 + d];
            float zv = zs[t * 68 + d];
            double df = (double)qv - (double)zv;
            ls += df * df;
            q[((size_t)(n * 64 + d)) * T_LEN + t0 + t] = qv;
        }
        dred[tid] = ls;
    }
    __syncthreads();
    for (int s = 128; s > 0; s >>= 1) {
        if (tid < s) dred[tid] += dred[tid + s];
        __syncthreads();
    }
    if (tid == 0) atomicAdd(loss, dred[0]);
}

extern "C" void kernel_launch(void* const* d_in, const int* in_sizes, int n_in,
                              void* d_out, int out_size, void* d_ws, size_t ws_size,
                              hipStream_t stream) {
    const float* x      = (const float*)d_in[0];
    const float* enc_w1 = (const float*)d_in[1];
    const float* enc_b1 = (const float*)d_in[2];
    const float* bn1_g  = (const float*)d_in[3];
    const float* bn1_b  = (const float*)d_in[4];
    const float* enc_w2 = (const float*)d_in[5];
    const float* enc_b2 = (const float*)d_in[6];
    const float* bn2_g  = (const float*)d_in[7];
    const float* bn2_b  = (const float*)d_in[8];
    const float* enc_w3 = (const float*)d_in[9];
    const float* enc_b3 = (const float*)d_in[10];
    const float* cb     = (const float*)d_in[11];
    const float* dec_w1 = (const float*)d_in[12];
    const float* dec_b1 = (const float*)d_in[13];
    const float* dbn1_g = (const float*)d_in[14];
    const float* dbn1_b = (const float*)d_in[15];
    const float* dec_w2 = (const float*)d_in[16];
    const float* dec_b2 = (const float*)d_in[17];
    const float* dbn2_g = (const float*)d_in[18];
    const float* dbn2_b = (const float*)d_in[19];
    const float* dec_w3 = (const float*)d_in[20];
    const float* dec_b3 = (const float*)d_in[21];

    float* wsf   = (float*)d_ws;
    float* outf  = (float*)d_out;
    float* A     = wsf + OFF_A;
    float* Bb    = wsf + OFF_B;
    float* Z     = wsf + OFF_Z;
    double2* st  = (double2*)(wsf + OFF_ST);
    double* lossp = (double*)(wsf + OFF_LOSS);
    double2* partA = (double2*)A;
    double2* partB = (double2*)Bb;
    double2* partZ = (double2*)Z;

    prep_k<<<1268, 256, 0, stream>>>(enc_w1, enc_w2, enc_w3,
                                     dec_w1, dec_w2, dec_w3, cb, wsf);

    // encoder: f64-vector, f64 LDS staging, fused BN-stat partials
    conv_k<80, 128, 3, false, true><<<dim3(512, 2), 256, 0, stream>>>(
        x, wsf + OFF_WT1, enc_b1, nullptr, A, partB, 512);
    stats2_k<<<1, 256, 0, stream>>>(partB, 128, 512, bn1_g, bn1_b, st,
                                    nullptr, nullptr);
    conv_k<128, 256, 3, true, true><<<dim3(512, 4), 256, 0, stream>>>(
        A, wsf + OFF_WT2, enc_b2, st, Bb, partZ, 512);
    stats2_k<<<1, 256, 0, stream>>>(partZ, 256, 512, bn2_g, bn2_b, st,
                                    nullptr, nullptr);
    conv_k<256, 64, 1, true, false><<<dim3(512, 1), 256, 0, stream>>>(
        Bb, wsf + OFF_WT3, enc_b3, st, Z, nullptr, 0);

    // vector quantizer — f32-formula scores, exact ref grid
    vq_k<<<1024, 256, 0, stream>>>(Z, cb, wsf + OFF_C2, Z,
                                   outf + 5242881, lossp);

    // decoder: split-bf16 MFMA, fused BN-stat partials; fin folded into stats2
    mbconv_k<64, 256, false, true><<<dim3(1024, 4), 256, 0, stream>>>(
        Z, wsf + OFF_WD1, dec_b1, nullptr, Bb, partA, 1024);
    stats2_k<<<2, 256, 0, stream>>>(partA, 256, 1024, dbn1_g, dbn1_b, st,
                                    lossp, outf + 5242880);
    mbconv_k<256, 128, true, true><<<dim3(1024, 2), 256, 0, stream>>>(
        Bb, wsf + OFF_WD2, dec_b2, st, A, partZ, 1024);
    stats2_k<<<1, 256, 0, stream>>>(partZ, 128, 1024, dbn2_g, dbn2_b, st,
                                    nullptr, nullptr);
    mbconv_k<128, 80, true, false><<<dim3(1024, 2), 256, 0, stream>>>(
        A, wsf + OFF_WD3, dec_b3, st, outf, nullptr, 0);
}